// Round 1
// 124.159 us; speedup vs baseline: 1.1298x; 1.1298x over previous
//
#include <hip/hip_runtime.h>
#include <math.h>

#define DIM 256
#define BATCH 16
#define NO 64
#define NI 512
#define NEG_SLOPE 0.01f
#define CSCALE 2.885390081777927f   // 2*log2(e): tanh(x) = 1 - 2/(exp2(CSCALE*x)+1)
#define OT 2                        // o's per attn thread

typedef float f32x4 __attribute__((ext_vector_type(4)));
typedef __bf16 bf16x8 __attribute__((ext_vector_type(8)));
typedef unsigned int u32x4 __attribute__((ext_vector_type(4)));

// ---------------------------------------------------------------------------
// Kernel 0: per-batch mask compaction. cnt[b] = #unmasked, idx[b][j] = i of
// j-th unmasked column, pos[b][i] = compacted slot (or -1 if masked).
// ---------------------------------------------------------------------------
__global__ __launch_bounds__(512) void mask_scan_kernel(
    const int* __restrict__ mask, int* __restrict__ idx,
    int* __restrict__ posArr, int* __restrict__ cnt)
{
  __shared__ int wtot[8];
  __shared__ int woff[8];
  const int b = blockIdx.x, t = threadIdx.x;
  const int lane = t & 63, wid = t >> 6;
  const int unm = (mask[b * NI + t] == 0) ? 1 : 0;
  unsigned long long bal = __ballot(unm);
  int my  = __popcll(bal & ((1ull << lane) - 1ull));
  if (lane == 0) wtot[wid] = __popcll(bal);
  __syncthreads();
  if (t == 0) {
    int acc = 0;
    for (int w = 0; w < 8; ++w) { woff[w] = acc; acc += wtot[w]; }
    cnt[b] = acc;
  }
  __syncthreads();
  int pos = woff[wid] + my;
  if (unm) idx[b * NI + pos] = t;
  posArr[b * NI + t] = unm ? pos : -1;
}

// ---------------------------------------------------------------------------
// split f32 -> bf16 hi (RNE, returned as low-16 bits) + exact f32 residual
// ---------------------------------------------------------------------------
__device__ __forceinline__ void split2(float f, unsigned int& hi16, float& lo) {
  unsigned int u = __builtin_bit_cast(unsigned int, f);
  unsigned int h = (u + 0x7FFFu + ((u >> 16) & 1u)) & 0xFFFF0000u; // RNE bf16, as f32 bits
  hi16 = h >> 16;
  lo = f - __builtin_bit_cast(float, h);   // exact (Sterbenz)
}
__device__ __forceinline__ unsigned int rne16(float f) {
  unsigned int u = __builtin_bit_cast(unsigned int, f);
  return (u + 0x7FFFu + ((u >> 16) & 1u)) >> 16;
}

struct __align__(8) U2 { unsigned int x, y; };

// ---------------------------------------------------------------------------
// Kernel 1 (blocks 0..575): GEMM  out[r,h] = sum_d A[r,d] * W1[h, coff+d]
// via split-bf16 3-pass MFMA (AhWh + AhWl + AlWh), fp32 accumulate.
//   rows 0..1023    -> Eq[bo][h] = exp2(CSCALE*(acc + b1[h]))  (A = q)
//   rows 1024..9215 -> Ek4[b][h/4][pos[i]][4] = exp2(CSCALE*acc)  (A = k,
//                      COMPACTED: masked columns dropped)
// 64x64 tile, 4 waves (2x2 grid of 32x32 wave-tiles), K-chunk 64.
// LDS rows padded to 72 bf16 (144 B) -> 2-way bank alias only (free).
// Blocks 576..591: Wf -> WfT transpose (unchanged).
// ---------------------------------------------------------------------------
#define OFF_AH 0
#define OFF_AL 9216
#define OFF_WH 18432
#define OFF_WL 27648

__global__ __launch_bounds__(256, 4) void proj_kernel(
    const float* __restrict__ q, const float* __restrict__ k,
    const float* __restrict__ W1, const float* __restrict__ b1,
    const float* __restrict__ Wf, const int* __restrict__ posArr,
    float* __restrict__ Eq, float* __restrict__ Ek4, float* __restrict__ WfT)
{
  __shared__ __align__(16) char smemRaw[36864];   // 36 KB

  const int t  = threadIdx.x;
  const int bx = blockIdx.x;

  if (bx >= 576) {                 // ---- Wf transpose path (unchanged) ----
    float* smem = (float*)smemRaw;
    const int tt = bx - 576;
    const int tr = tt >> 2, tc = tt & 3;
#pragma unroll
    for (int p = 0; p < 4; ++p) {
      int idx2 = p * 256 + t;
      int row = idx2 >> 4, j = idx2 & 15;
      float4 vv = *(const float4*)(Wf + (size_t)(tr * 64 + row) * 256 + tc * 64 + j * 4);
      *(float4*)&smem[row * 68 + j * 4] = vv;
    }
    __syncthreads();
#pragma unroll
    for (int p = 0; p < 4; ++p) {
      int idx2 = p * 256 + t;
      int row = idx2 >> 4, j = idx2 & 15;
      float4 ov;
      ov.x = smem[(j * 4 + 0) * 68 + row];
      ov.y = smem[(j * 4 + 1) * 68 + row];
      ov.z = smem[(j * 4 + 2) * 68 + row];
      ov.w = smem[(j * 4 + 3) * 68 + row];
      *(float4*)(WfT + (size_t)(tc * 64 + row) * 256 + tr * 64 + j * 4) = ov;
    }
    return;
  }

  const int mt = bx >> 2;
  const int nt = bx & 3;
  const int r0 = mt * 64;
  const int h0 = nt * 64;
  const bool isq = (r0 < BATCH * NO);
  const float* src = isq ? (q + (size_t)r0 * DIM)
                         : (k + (size_t)(r0 - BATCH * NO) * DIM);
  const int coff = isq ? 0 : DIM;

  // staging mapping: idx = p*256+t -> row = idx>>4 (0..63), c4 = idx&15
  const int srow = t >> 4;           // rows srow, srow+16, srow+32, srow+48
  const int sc4  = t & 15;

  const int lane = t & 63, w = t >> 6;
  const int m0w = (w >> 1) * 32, n0w = (w & 1) * 32;
  const int lr = lane & 15, lg = lane >> 4;

  f32x4 acc[2][2] = {};

  float4 aR[4], wR[4];
#define LOADC(c0_)                                                              \
  _Pragma("unroll")                                                             \
  for (int p = 0; p < 4; ++p) {                                                 \
    int row = srow + p * 16;                                                    \
    aR[p] = *(const float4*)(src + (size_t)row * DIM + (c0_) + sc4 * 4);        \
    wR[p] = *(const float4*)(W1 + (size_t)(h0 + row) * (2 * DIM) + coff + (c0_) + sc4 * 4); \
  }

  LOADC(0)

  for (int c = 0; c < 4; ++c) {
    // ---- convert chunk c (in regs) to bf16 hi/lo and stage to LDS ----
#pragma unroll
    for (int p = 0; p < 4; ++p) {
      int row = srow + p * 16;
      int boff = row * 144 + sc4 * 8;     // byte offset within each array
      unsigned int h0_, h1_, h2_, h3_;
      float l0, l1, l2, l3;
      split2(aR[p].x, h0_, l0); split2(aR[p].y, h1_, l1);
      split2(aR[p].z, h2_, l2); split2(aR[p].w, h3_, l3);
      *(U2*)(smemRaw + OFF_AH + boff) = { h0_ | (h1_ << 16), h2_ | (h3_ << 16) };
      *(U2*)(smemRaw + OFF_AL + boff) = { rne16(l0) | (rne16(l1) << 16),
                                          rne16(l2) | (rne16(l3) << 16) };
      split2(wR[p].x, h0_, l0); split2(wR[p].y, h1_, l1);
      split2(wR[p].z, h2_, l2); split2(wR[p].w, h3_, l3);
      *(U2*)(smemRaw + OFF_WH + boff) = { h0_ | (h1_ << 16), h2_ | (h3_ << 16) };
      *(U2*)(smemRaw + OFF_WL + boff) = { rne16(l0) | (rne16(l1) << 16),
                                          rne16(l2) | (rne16(l3) << 16) };
    }
    __syncthreads();

    if (c < 3) { LOADC((c + 1) * 64) }   // issue-early: flies under the MFMAs

    // ---- MFMA over this 64-wide K chunk: 2 k-steps of 32 ----
#pragma unroll
    for (int kk = 0; kk < 2; ++kk) {
      const int kb = kk * 64 + lg * 16;  // byte offset of this lane's 8 bf16
      bf16x8 ah[2], al[2], bh[2], bl[2];
#pragma unroll
      for (int mi = 0; mi < 2; ++mi) {
        int row = m0w + mi * 16 + lr;
        ah[mi] = __builtin_bit_cast(bf16x8, *(const u32x4*)(smemRaw + OFF_AH + row * 144 + kb));
        al[mi] = __builtin_bit_cast(bf16x8, *(const u32x4*)(smemRaw + OFF_AL + row * 144 + kb));
      }
#pragma unroll
      for (int ni = 0; ni < 2; ++ni) {
        int row = n0w + ni * 16 + lr;
        bh[ni] = __builtin_bit_cast(bf16x8, *(const u32x4*)(smemRaw + OFF_WH + row * 144 + kb));
        bl[ni] = __builtin_bit_cast(bf16x8, *(const u32x4*)(smemRaw + OFF_WL + row * 144 + kb));
      }
#pragma unroll
      for (int mi = 0; mi < 2; ++mi)
#pragma unroll
        for (int ni = 0; ni < 2; ++ni) {
          acc[mi][ni] = __builtin_amdgcn_mfma_f32_16x16x32_bf16(ah[mi], bh[ni], acc[mi][ni], 0, 0, 0);
          acc[mi][ni] = __builtin_amdgcn_mfma_f32_16x16x32_bf16(ah[mi], bl[ni], acc[mi][ni], 0, 0, 0);
          acc[mi][ni] = __builtin_amdgcn_mfma_f32_16x16x32_bf16(al[mi], bh[ni], acc[mi][ni], 0, 0, 0);
        }
    }
    __syncthreads();
  }

  // ---- epilogue. C/D layout (m89-verified): col(n)=lane&15, row(m)=(lane>>4)*4+reg
  if (isq) {
#pragma unroll
    for (int ni = 0; ni < 2; ++ni) {
      int h = h0 + n0w + ni * 16 + lr;
      float b1v = b1[h];
#pragma unroll
      for (int mi = 0; mi < 2; ++mi)
#pragma unroll
        for (int rg = 0; rg < 4; ++rg) {
          int r = r0 + m0w + mi * 16 + lg * 4 + rg;
          Eq[(size_t)r * DIM + h] =
              __builtin_amdgcn_exp2f((acc[mi][ni][rg] + b1v) * CSCALE);
        }
    }
  } else {
    const int rk0 = r0 - BATCH * NO;
    const int b = rk0 >> 9;
    const int ib = rk0 & 511;
#pragma unroll
    for (int mi = 0; mi < 2; ++mi)
#pragma unroll
      for (int rg = 0; rg < 4; ++rg) {
        int i = ib + m0w + mi * 16 + lg * 4 + rg;
        int pos = posArr[b * NI + i];
        if (pos >= 0) {
#pragma unroll
          for (int ni = 0; ni < 2; ++ni) {
            int h = h0 + n0w + ni * 16 + lr;
            Ek4[((size_t)(b * 64 + (h >> 2)) * NI + pos) * 4 + (h & 3)] =
                __builtin_amdgcn_exp2f(acc[mi][ni][rg] * CSCALE);
          }
        }
      }
  }
}

__device__ __forceinline__ void f4arr(float4 v, float* a) {
  a[0] = v.x; a[1] = v.y; a[2] = v.z; a[3] = v.w;
}

// ---------------------------------------------------------------------------
// Kernel 2: one block (512 threads) per (b, o-pair). Grid 512. XCD-swizzled.
// (unchanged this round — isolating the proj MFMA change)
// ---------------------------------------------------------------------------
__global__ __launch_bounds__(512, 4) void attn_kernel(
    const float* __restrict__ Eq, const float* __restrict__ Ek4,
    const float* __restrict__ v, const int* __restrict__ idx,
    const int* __restrict__ posArr, const int* __restrict__ cnt,
    const float* __restrict__ W2, const float* __restrict__ b2,
    const float* __restrict__ WfT, const float* __restrict__ bf,
    float* __restrict__ out, float* __restrict__ attn_out)
{
  __shared__ float sc[OT][NI];        // 4 KB (compacted attn weights)
  __shared__ int   idxs[NI];          // 2 KB
  __shared__ float pvp[8][OT][DIM];   // 16 KB
  __shared__ float o0[OT][DIM];       // 2 KB
  __shared__ float red4[8][OT];
  __shared__ float redw[8];

  const int t    = threadIdx.x;
  const int lane = t & 63;
  const int wid  = t >> 6;

  const int blk  = blockIdx.x;
  const int tile = (blk & 7) * 64 + (blk >> 3);   // XCD swizzle
  const int b    = tile >> 5;
  const int bo0  = b * 64 + (tile & 31) * OT;

  const int cntb = cnt[b];
  idxs[t] = idx[b * NI + t];
  const int myPos = posArr[b * NI + t];    // for attn_out scatter-back

  // ---- sumW2 ----
  float partial = (t < DIM) ? W2[t] : 0.f;
#pragma unroll
  for (int off = 32; off >= 1; off >>= 1) partial += __shfl_xor(partial, off, 64);
  if (lane == 0) redw[wid] = partial;
  __syncthreads();
  float sumw2 = 0.f;
#pragma unroll
  for (int w = 0; w < 8; ++w) sumw2 += redw[w];
  const float base = sumw2 + b2[0];

  // ---- phase 1: scores for compacted column j = t (paired-rcp) ----
  const int j = t;
  const bool active = (j < cntb);
  const int jc = active ? j : (cntb > 0 ? cntb - 1 : 0);   // clamped safe index
  const float4* kb4 = (const float4*)Ek4 + (size_t)b * 64 * NI;  // [hq*NI + j]
  const float* qrow0 = Eq + (size_t)(bo0 + 0) * DIM;
  const float* qrow1 = Eq + (size_t)(bo0 + 1) * DIM;

  float acc0 = 0.f, acc1 = 0.f;
  if (wid * 64 < cntb) {                 // wave-uniform skip of dead waves
#pragma unroll 8
    for (int hq = 0; hq < 64; ++hq) {
      float4 kq = kb4[(size_t)hq * NI + jc];
      float wr[4], q0r[4], q1r[4], kv[4];
      f4arr(*(const float4*)(W2 + hq * 4), wr);      // wave-uniform -> s_load
      f4arr(*(const float4*)(qrow0 + hq * 4), q0r);
      f4arr(*(const float4*)(qrow1 + hq * 4), q1r);
      f4arr(kq, kv);
#pragma unroll
      for (int pr = 0; pr < 2; ++pr) {               // pairs (0,1), (2,3)
        const int ea = pr * 2, eb = pr * 2 + 1;
        float A0 = fmaf(q0r[ea], kv[ea], 1.f);
        float B0 = fmaf(q0r[eb], kv[eb], 1.f);
        float N0 = fmaf(wr[eb], A0, wr[ea] * B0);
        acc0 = fmaf(N0, __builtin_amdgcn_rcpf(A0 * B0), acc0);
        float A1 = fmaf(q1r[ea], kv[ea], 1.f);
        float B1 = fmaf(q1r[eb], kv[eb], 1.f);
        float N1 = fmaf(wr[eb], A1, wr[ea] * B1);
        acc1 = fmaf(N1, __builtin_amdgcn_rcpf(A1 * B1), acc1);
      }
    }
  }

  float s0 = active ? (base - 2.f * acc0) : -INFINITY;
  float s1 = active ? (base - 2.f * acc1) : -INFINITY;

  // ---- phase 2: softmax over compacted set, no max-subtraction ----
  float p0 = __builtin_amdgcn_exp2f(s0 * 1.4426950408889634f);
  float p1 = __builtin_amdgcn_exp2f(s1 * 1.4426950408889634f);
  float ps0 = p0, ps1 = p1;
#pragma unroll
  for (int off = 32; off >= 1; off >>= 1) {
    ps0 += __shfl_xor(ps0, off, 64);
    ps1 += __shfl_xor(ps1, off, 64);
  }
  __syncthreads();               // redw reads done; red4 safe
  if (lane == 0) { red4[wid][0] = ps0; red4[wid][1] = ps1; }
  __syncthreads();
  float ss0 = 0.f, ss1 = 0.f;
#pragma unroll
  for (int w = 0; w < 8; ++w) { ss0 += red4[w][0]; ss1 += red4[w][1]; }
  const float a0 = p0 * __builtin_amdgcn_rcpf(ss0);
  const float a1 = p1 * __builtin_amdgcn_rcpf(ss1);
  sc[0][j] = a0;                 // compacted slot (0 for inactive j)
  sc[1][j] = a1;
  __syncthreads();

  // attn_out scatter-back: original column i = t; masked -> exact 0
  {
    float w0 = (myPos >= 0) ? sc[0][myPos] : 0.f;
    float w1 = (myPos >= 0) ? sc[1][myPos] : 0.f;
    attn_out[(size_t)(bo0 + 0) * NI + t] = w0;
    attn_out[(size_t)(bo0 + 1) * NI + t] = w1;
  }

  // ---- phase 3: PV over compacted rows. wave wid: j in [wid*64, +64)∩cnt ----
  {
    const int d4 = lane;
    float4 av0 = {0.f, 0.f, 0.f, 0.f};
    float4 av1 = {0.f, 0.f, 0.f, 0.f};
    const float4* vb4 = (const float4*)(v + (size_t)b * NI * DIM);
    const int jend = min(wid * 64 + 64, cntb);
#pragma unroll 4
    for (int jb = wid * 64; jb < jend; ++jb) {
      int row = idxs[jb];                      // LDS broadcast (uniform)
      float sa0 = sc[0][jb], sa1 = sc[1][jb];  // LDS broadcast
      float4 vv = vb4[(size_t)row * 64 + d4];
      av0.x = fmaf(sa0, vv.x, av0.x);
      av0.y = fmaf(sa0, vv.y, av0.y);
      av0.z = fmaf(sa0, vv.z, av0.z);
      av0.w = fmaf(sa0, vv.w, av0.w);
      av1.x = fmaf(sa1, vv.x, av1.x);
      av1.y = fmaf(sa1, vv.y, av1.y);
      av1.z = fmaf(sa1, vv.z, av1.z);
      av1.w = fmaf(sa1, vv.w, av1.w);
    }
    *(float4*)&pvp[wid][0][d4 * 4] = av0;      // dead waves store zeros
    *(float4*)&pvp[wid][1][d4 * 4] = av1;
  }
  __syncthreads();
  {
    int oo = t >> 8, d = t & 255;
    float sacc = 0.f;
#pragma unroll
    for (int w = 0; w < 8; ++w) sacc += pvp[w][oo][d];
    o0[oo][d] = sacc;
  }
  __syncthreads();

  // ---- phase 4: threads t<256 compute BOTH o's, one WfT column load ----
  if (t < DIM) {
    const int d = t;
    float f0 = 0.f, f1 = 0.f;
#pragma unroll 8
    for (int e4 = 0; e4 < 64; ++e4) {
      float oa[4], ob[4];
      f4arr(*(const float4*)&o0[0][e4 * 4], oa);
      f4arr(*(const float4*)&o0[1][e4 * 4], ob);
#pragma unroll
      for (int c = 0; c < 4; ++c) {
        float wv = WfT[(size_t)(e4 * 4 + c) * DIM + d];
        f0 = fmaf(oa[c], wv, f0);
        f1 = fmaf(ob[c], wv, f1);
      }
    }
    float bfv = bf[d];
    f0 += bfv; f1 += bfv;
    f0 = (f0 >= 0.f) ? f0 : NEG_SLOPE * f0;
    f1 = (f1 >= 0.f) ? f1 : NEG_SLOPE * f1;
    out[(size_t)(bo0 + 0) * DIM + d] = f0;
    out[(size_t)(bo0 + 1) * DIM + d] = f1;
  }
}

// ---------------------------------------------------------------------------
extern "C" void kernel_launch(void* const* d_in, const int* in_sizes, int n_in,
                              void* d_out, int out_size, void* d_ws, size_t ws_size,
                              hipStream_t stream) {
  const float* q    = (const float*)d_in[0];
  const float* k    = (const float*)d_in[1];
  const float* v    = (const float*)d_in[2];
  const int*   mask = (const int*)d_in[3];
  const float* W1   = (const float*)d_in[4];
  const float* b1   = (const float*)d_in[5];
  const float* W2   = (const float*)d_in[6];
  const float* b2   = (const float*)d_in[7];
  const float* Wf   = (const float*)d_in[8];
  const float* bf   = (const float*)d_in[9];

  float* out      = (float*)d_out;                    // (16,64,256)
  float* attn_out = out + (size_t)BATCH * NO * DIM;   // (16,64,512)

  float* Eq   = (float*)d_ws;                         // 1024 x 256
  float* Ek4  = Eq + (size_t)BATCH * NO * DIM;        // 16 x 64 x 512 x 4
  float* WfT  = Ek4 + (size_t)BATCH * DIM * NI;       // 256 x 256
  int*   idx  = (int*)(WfT + (size_t)DIM * DIM);      // 16 x 512
  int*   pos  = idx + BATCH * NI;                     // 16 x 512
  int*   cnt  = pos + BATCH * NI;                     // 16

  mask_scan_kernel<<<BATCH, 512, 0, stream>>>(mask, idx, pos, cnt);
  proj_kernel<<<592, 256, 0, stream>>>(q, k, W1, b1, Wf, pos, Eq, Ek4, WfT);
  attn_kernel<<<(BATCH * NO) / OT, 512, 0, stream>>>(Eq, Ek4, v, idx, pos, cnt,
                                                     W2, b2, WfT, bf, out, attn_out);
}

// Round 2
// 121.616 us; speedup vs baseline: 1.1535x; 1.0209x over previous
//
#include <hip/hip_runtime.h>
#include <math.h>

#define DIM 256
#define BATCH 16
#define NO 64
#define NI 512
#define NEG_SLOPE 0.01f
#define CSCALE 2.885390081777927f   // 2*log2(e): tanh(x) = 1 - 2/(exp2(CSCALE*x)+1)
#define OT 2                        // o's per attn thread

typedef float f32x4 __attribute__((ext_vector_type(4)));
typedef __bf16 bf16x8 __attribute__((ext_vector_type(8)));
typedef unsigned int u32x4 __attribute__((ext_vector_type(4)));

// ---------------------------------------------------------------------------
// split f32 -> bf16 hi (RNE, returned as low-16 bits) + exact f32 residual
// ---------------------------------------------------------------------------
__device__ __forceinline__ void split2(float f, unsigned int& hi16, float& lo) {
  unsigned int u = __builtin_bit_cast(unsigned int, f);
  unsigned int h = (u + 0x7FFFu + ((u >> 16) & 1u)) & 0xFFFF0000u; // RNE bf16, as f32 bits
  hi16 = h >> 16;
  lo = f - __builtin_bit_cast(float, h);   // exact (Sterbenz)
}
__device__ __forceinline__ unsigned int rne16(float f) {
  unsigned int u = __builtin_bit_cast(unsigned int, f);
  return (u + 0x7FFFu + ((u >> 16) & 1u)) >> 16;
}

struct __align__(8) U2 { unsigned int x, y; };

// ---------------------------------------------------------------------------
// Kernel 1 (blocks 0..575): GEMM  out[r,h] = sum_d A[r,d] * W1[h, coff+d]
// via split-bf16 3-pass MFMA (AhWh + AhWl + AlWh), fp32 accumulate.
//   blocks 0..63   (q): Eq[bo][h] = exp2(CSCALE*(acc + b1[h]))
//   blocks 64..575 (k): MASK-COMPACTED GEMM. Each block inlines the batch
//     mask scan (ballot prefix over 512 entries), owns compacted slots
//     [jb0, jb0+64), gathers only unmasked k rows, and exits immediately if
//     jb0 >= cnt[b] (~half the k blocks with Bernoulli(0.5) mask).
//     Ek4[b][h/4][pos][4] with pos = jb0 + local (dense, no indirection).
// 64x64 tile, 4 waves (2x2 grid of 32x32 wave-tiles), K-chunk 64.
// LDS rows padded to 72 bf16 (144 B) -> 2-way bank alias only (free).
// Blocks 576..591: Wf -> WfT transpose.
// ---------------------------------------------------------------------------
#define OFF_AH 0
#define OFF_AL 9216
#define OFF_WH 18432
#define OFF_WL 27648

__global__ __launch_bounds__(256, 4) void proj_kernel(
    const float* __restrict__ q, const float* __restrict__ k,
    const float* __restrict__ W1, const float* __restrict__ b1,
    const float* __restrict__ Wf, const int* __restrict__ mask,
    float* __restrict__ Eq, float* __restrict__ Ek4, float* __restrict__ WfT)
{
  __shared__ __align__(16) char smemRaw[36864];   // 36 KB
  __shared__ int idx_s[64];                       // gather window
  __shared__ int swtot[4];

  const int t  = threadIdx.x;
  const int bx = blockIdx.x;

  if (bx >= 576) {                 // ---- Wf transpose path ----
    float* smem = (float*)smemRaw;
    const int tt = bx - 576;
    const int tr = tt >> 2, tc = tt & 3;
#pragma unroll
    for (int p = 0; p < 4; ++p) {
      int idx2 = p * 256 + t;
      int row = idx2 >> 4, j = idx2 & 15;
      float4 vv = *(const float4*)(Wf + (size_t)(tr * 64 + row) * 256 + tc * 64 + j * 4);
      *(float4*)&smem[row * 68 + j * 4] = vv;
    }
    __syncthreads();
#pragma unroll
    for (int p = 0; p < 4; ++p) {
      int idx2 = p * 256 + t;
      int row = idx2 >> 4, j = idx2 & 15;
      float4 ov;
      ov.x = smem[(j * 4 + 0) * 68 + row];
      ov.y = smem[(j * 4 + 1) * 68 + row];
      ov.z = smem[(j * 4 + 2) * 68 + row];
      ov.w = smem[(j * 4 + 3) * 68 + row];
      *(float4*)(WfT + (size_t)(tc * 64 + row) * 256 + tr * 64 + j * 4) = ov;
    }
    return;
  }

  const int mt = bx >> 2;
  const int nt = bx & 3;
  const int h0 = nt * 64;
  const bool isq = (mt < 16);

  const int srow = t >> 4;           // staging rows: srow + {0,16,32,48}
  const int sc4  = t & 15;
  const int lane = t & 63, w = t >> 6;
  const int m0w = (w >> 1) * 32, n0w = (w & 1) * 32;
  const int lr = lane & 15, lg = lane >> 4;

  const float* src;
  int coff, bb = 0, jb0 = 0, cntb = 0;
  int rowg[4];

  if (isq) {
    src  = q + (size_t)(mt * 64) * DIM;
    coff = 0;
#pragma unroll
    for (int p = 0; p < 4; ++p) rowg[p] = srow + p * 16;
  } else {
    const int ki = mt - 16;          // 0..127
    bb  = ki >> 3;                   // batch
    jb0 = (ki & 7) * 64;             // compacted window start
    // ---- inline mask scan: thread t handles entries 2t, 2t+1 ----
    const int e0 = (mask[bb * NI + 2 * t] == 0);
    const int e1 = (mask[bb * NI + 2 * t + 1] == 0);
    const int ps = e0 + e1;
    int x = ps;
#pragma unroll
    for (int off = 1; off < 64; off <<= 1) {
      int y = __shfl_up(x, off, 64);
      if (lane >= off) x += y;
    }
    if (lane == 63) swtot[w] = x;
    if (t < 64) idx_s[t] = 0;        // safe default for tail rows
    __syncthreads();
    int woffv = 0;
#pragma unroll
    for (int w2 = 0; w2 < 4; ++w2) {
      int v_ = swtot[w2];
      if (w2 < w) woffv += v_;
      cntb += v_;
    }
    const int excl = woffv + x - ps;          // prefix before entry 2t
    const int p0 = excl, p1 = excl + e0;
    if (e0 && p0 >= jb0 && p0 < jb0 + 64) idx_s[p0 - jb0] = 2 * t;
    if (e1 && p1 >= jb0 && p1 < jb0 + 64) idx_s[p1 - jb0] = 2 * t + 1;
    __syncthreads();
    if (jb0 >= cntb) return;         // block-uniform: nothing to do
    src  = k + (size_t)bb * NI * DIM;
    coff = DIM;
#pragma unroll
    for (int p = 0; p < 4; ++p) rowg[p] = idx_s[srow + p * 16];
  }

  f32x4 acc[2][2] = {};

  float4 aR[4], wR[4];
#define LOADC(c0_)                                                              \
  _Pragma("unroll")                                                             \
  for (int p = 0; p < 4; ++p) {                                                 \
    aR[p] = *(const float4*)(src + (size_t)rowg[p] * DIM + (c0_) + sc4 * 4);    \
    wR[p] = *(const float4*)(W1 + (size_t)(h0 + srow + p * 16) * (2 * DIM) + coff + (c0_) + sc4 * 4); \
  }

  LOADC(0)

  for (int c = 0; c < 4; ++c) {
    // ---- convert chunk c (in regs) to bf16 hi/lo and stage to LDS ----
#pragma unroll
    for (int p = 0; p < 4; ++p) {
      int row = srow + p * 16;
      int boff = row * 144 + sc4 * 8;     // byte offset within each array
      unsigned int h0_, h1_, h2_, h3_;
      float l0, l1, l2, l3;
      split2(aR[p].x, h0_, l0); split2(aR[p].y, h1_, l1);
      split2(aR[p].z, h2_, l2); split2(aR[p].w, h3_, l3);
      *(U2*)(smemRaw + OFF_AH + boff) = { h0_ | (h1_ << 16), h2_ | (h3_ << 16) };
      *(U2*)(smemRaw + OFF_AL + boff) = { rne16(l0) | (rne16(l1) << 16),
                                          rne16(l2) | (rne16(l3) << 16) };
      split2(wR[p].x, h0_, l0); split2(wR[p].y, h1_, l1);
      split2(wR[p].z, h2_, l2); split2(wR[p].w, h3_, l3);
      *(U2*)(smemRaw + OFF_WH + boff) = { h0_ | (h1_ << 16), h2_ | (h3_ << 16) };
      *(U2*)(smemRaw + OFF_WL + boff) = { rne16(l0) | (rne16(l1) << 16),
                                          rne16(l2) | (rne16(l3) << 16) };
    }
    __syncthreads();

    if (c < 3) { LOADC((c + 1) * 64) }   // issue-early: flies under the MFMAs

    // ---- MFMA over this 64-wide K chunk: 2 k-steps of 32 ----
#pragma unroll
    for (int kk = 0; kk < 2; ++kk) {
      const int kb = kk * 64 + lg * 16;  // byte offset of this lane's 8 bf16
      bf16x8 ah[2], al[2], bh[2], bl[2];
#pragma unroll
      for (int mi = 0; mi < 2; ++mi) {
        int row = m0w + mi * 16 + lr;
        ah[mi] = __builtin_bit_cast(bf16x8, *(const u32x4*)(smemRaw + OFF_AH + row * 144 + kb));
        al[mi] = __builtin_bit_cast(bf16x8, *(const u32x4*)(smemRaw + OFF_AL + row * 144 + kb));
      }
#pragma unroll
      for (int ni = 0; ni < 2; ++ni) {
        int row = n0w + ni * 16 + lr;
        bh[ni] = __builtin_bit_cast(bf16x8, *(const u32x4*)(smemRaw + OFF_WH + row * 144 + kb));
        bl[ni] = __builtin_bit_cast(bf16x8, *(const u32x4*)(smemRaw + OFF_WL + row * 144 + kb));
      }
#pragma unroll
      for (int mi = 0; mi < 2; ++mi)
#pragma unroll
        for (int ni = 0; ni < 2; ++ni) {
          acc[mi][ni] = __builtin_amdgcn_mfma_f32_16x16x32_bf16(ah[mi], bh[ni], acc[mi][ni], 0, 0, 0);
          acc[mi][ni] = __builtin_amdgcn_mfma_f32_16x16x32_bf16(ah[mi], bl[ni], acc[mi][ni], 0, 0, 0);
          acc[mi][ni] = __builtin_amdgcn_mfma_f32_16x16x32_bf16(al[mi], bh[ni], acc[mi][ni], 0, 0, 0);
        }
    }
    __syncthreads();
  }

  // ---- epilogue. C/D layout (m89-verified): col(n)=lane&15, row(m)=(lane>>4)*4+reg
  if (isq) {
    const int r0 = mt * 64;
#pragma unroll
    for (int ni = 0; ni < 2; ++ni) {
      int h = h0 + n0w + ni * 16 + lr;
      float b1v = b1[h];
#pragma unroll
      for (int mi = 0; mi < 2; ++mi)
#pragma unroll
        for (int rg = 0; rg < 4; ++rg) {
          int r = r0 + m0w + mi * 16 + lg * 4 + rg;
          Eq[(size_t)r * DIM + h] =
              __builtin_amdgcn_exp2f((acc[mi][ni][rg] + b1v) * CSCALE);
        }
    }
  } else {
    const int lim = cntb - jb0;      // valid local rows in this window
#pragma unroll
    for (int mi = 0; mi < 2; ++mi)
#pragma unroll
      for (int rg = 0; rg < 4; ++rg) {
        int local = m0w + mi * 16 + lg * 4 + rg;
        if (local < lim) {
          int pos = jb0 + local;     // dense compacted slot
#pragma unroll
          for (int ni = 0; ni < 2; ++ni) {
            int h = h0 + n0w + ni * 16 + lr;
            Ek4[((size_t)(bb * 64 + (h >> 2)) * NI + pos) * 4 + (h & 3)] =
                __builtin_amdgcn_exp2f(acc[mi][ni][rg] * CSCALE);
          }
        }
      }
  }
}

__device__ __forceinline__ void f4arr(float4 v, float* a) {
  a[0] = v.x; a[1] = v.y; a[2] = v.z; a[3] = v.w;
}

// ---------------------------------------------------------------------------
// Kernel 2: one block (512 threads) per (b, o-pair). Grid 512. XCD-swizzled.
// Inlines its own mask scan (ballot prefix) -> idxs/myPos/cntb; no global
// idx/pos/cnt arrays, no mask_scan kernel.
// ---------------------------------------------------------------------------
__global__ __launch_bounds__(512, 4) void attn_kernel(
    const float* __restrict__ Eq, const float* __restrict__ Ek4,
    const float* __restrict__ v, const int* __restrict__ mask,
    const float* __restrict__ W2, const float* __restrict__ b2,
    const float* __restrict__ WfT, const float* __restrict__ bf,
    float* __restrict__ out, float* __restrict__ attn_out)
{
  __shared__ float sc[OT][NI];        // 4 KB (compacted attn weights)
  __shared__ int   idxs[NI];          // 2 KB
  __shared__ float pvp[8][OT][DIM];   // 16 KB
  __shared__ float o0[OT][DIM];       // 2 KB
  __shared__ float red4[8][OT];
  __shared__ float redw[8];
  __shared__ int   swtot8[8];

  const int t    = threadIdx.x;
  const int lane = t & 63;
  const int wid  = t >> 6;

  const int blk  = blockIdx.x;
  const int tile = (blk & 7) * 64 + (blk >> 3);   // XCD swizzle
  const int b    = tile >> 5;
  const int bo0  = b * 64 + (tile & 31) * OT;

  // ---- inline mask scan (was mask_scan_kernel) ----
  const int unm = (mask[b * NI + t] == 0) ? 1 : 0;
  unsigned long long bal = __ballot(unm);
  int my = __popcll(bal & ((1ull << lane) - 1ull));
  if (lane == 0) swtot8[wid] = __popcll(bal);

  // ---- sumW2 (overlapped with scan barrier) ----
  float partial = (t < DIM) ? W2[t] : 0.f;
#pragma unroll
  for (int off = 32; off >= 1; off >>= 1) partial += __shfl_xor(partial, off, 64);
  if (lane == 0) redw[wid] = partial;
  __syncthreads();

  int cntb = 0, woffv = 0;
#pragma unroll
  for (int w = 0; w < 8; ++w) {
    int v_ = swtot8[w];
    if (w < wid) woffv += v_;
    cntb += v_;
  }
  const int myPos = unm ? (woffv + my) : -1;
  if (unm) idxs[myPos] = t;          // read in phase 3, after barriers

  float sumw2 = 0.f;
#pragma unroll
  for (int w = 0; w < 8; ++w) sumw2 += redw[w];
  const float base = sumw2 + b2[0];

  // ---- phase 1: scores for compacted column j = t (paired-rcp) ----
  const int j = t;
  const bool active = (j < cntb);
  const int jc = active ? j : (cntb > 0 ? cntb - 1 : 0);   // clamped safe index
  const float4* kb4 = (const float4*)Ek4 + (size_t)b * 64 * NI;  // [hq*NI + j]
  const float* qrow0 = Eq + (size_t)(bo0 + 0) * DIM;
  const float* qrow1 = Eq + (size_t)(bo0 + 1) * DIM;

  float acc0 = 0.f, acc1 = 0.f;
  if (wid * 64 < cntb) {                 // wave-uniform skip of dead waves
#pragma unroll 8
    for (int hq = 0; hq < 64; ++hq) {
      float4 kq = kb4[(size_t)hq * NI + jc];
      float wr[4], q0r[4], q1r[4], kv[4];
      f4arr(*(const float4*)(W2 + hq * 4), wr);      // wave-uniform -> s_load
      f4arr(*(const float4*)(qrow0 + hq * 4), q0r);
      f4arr(*(const float4*)(qrow1 + hq * 4), q1r);
      f4arr(kq, kv);
#pragma unroll
      for (int pr = 0; pr < 2; ++pr) {               // pairs (0,1), (2,3)
        const int ea = pr * 2, eb = pr * 2 + 1;
        float A0 = fmaf(q0r[ea], kv[ea], 1.f);
        float B0 = fmaf(q0r[eb], kv[eb], 1.f);
        float N0 = fmaf(wr[eb], A0, wr[ea] * B0);
        acc0 = fmaf(N0, __builtin_amdgcn_rcpf(A0 * B0), acc0);
        float A1 = fmaf(q1r[ea], kv[ea], 1.f);
        float B1 = fmaf(q1r[eb], kv[eb], 1.f);
        float N1 = fmaf(wr[eb], A1, wr[ea] * B1);
        acc1 = fmaf(N1, __builtin_amdgcn_rcpf(A1 * B1), acc1);
      }
    }
  }

  float s0 = active ? (base - 2.f * acc0) : -INFINITY;
  float s1 = active ? (base - 2.f * acc1) : -INFINITY;

  // ---- phase 2: softmax over compacted set, no max-subtraction ----
  float p0 = __builtin_amdgcn_exp2f(s0 * 1.4426950408889634f);
  float p1 = __builtin_amdgcn_exp2f(s1 * 1.4426950408889634f);
  float ps0 = p0, ps1 = p1;
#pragma unroll
  for (int off = 32; off >= 1; off >>= 1) {
    ps0 += __shfl_xor(ps0, off, 64);
    ps1 += __shfl_xor(ps1, off, 64);
  }
  __syncthreads();               // redw reads done; red4 safe
  if (lane == 0) { red4[wid][0] = ps0; red4[wid][1] = ps1; }
  __syncthreads();
  float ss0 = 0.f, ss1 = 0.f;
#pragma unroll
  for (int w = 0; w < 8; ++w) { ss0 += red4[w][0]; ss1 += red4[w][1]; }
  const float a0 = p0 * __builtin_amdgcn_rcpf(ss0);
  const float a1 = p1 * __builtin_amdgcn_rcpf(ss1);
  sc[0][j] = a0;                 // compacted slot (0 for inactive j)
  sc[1][j] = a1;
  __syncthreads();

  // attn_out scatter-back: original column i = t; masked -> exact 0
  {
    float w0 = (myPos >= 0) ? sc[0][myPos] : 0.f;
    float w1 = (myPos >= 0) ? sc[1][myPos] : 0.f;
    attn_out[(size_t)(bo0 + 0) * NI + t] = w0;
    attn_out[(size_t)(bo0 + 1) * NI + t] = w1;
  }

  // ---- phase 3: PV over compacted rows. wave wid: j in [wid*64, +64)∩cnt ----
  {
    const int d4 = lane;
    float4 av0 = {0.f, 0.f, 0.f, 0.f};
    float4 av1 = {0.f, 0.f, 0.f, 0.f};
    const float4* vb4 = (const float4*)(v + (size_t)b * NI * DIM);
    const int jend = min(wid * 64 + 64, cntb);
#pragma unroll 4
    for (int jb = wid * 64; jb < jend; ++jb) {
      int row = idxs[jb];                      // LDS broadcast (uniform)
      float sa0 = sc[0][jb], sa1 = sc[1][jb];  // LDS broadcast
      float4 vv = vb4[(size_t)row * 64 + d4];
      av0.x = fmaf(sa0, vv.x, av0.x);
      av0.y = fmaf(sa0, vv.y, av0.y);
      av0.z = fmaf(sa0, vv.z, av0.z);
      av0.w = fmaf(sa0, vv.w, av0.w);
      av1.x = fmaf(sa1, vv.x, av1.x);
      av1.y = fmaf(sa1, vv.y, av1.y);
      av1.z = fmaf(sa1, vv.z, av1.z);
      av1.w = fmaf(sa1, vv.w, av1.w);
    }
    *(float4*)&pvp[wid][0][d4 * 4] = av0;      // dead waves store zeros
    *(float4*)&pvp[wid][1][d4 * 4] = av1;
  }
  __syncthreads();
  {
    int oo = t >> 8, d = t & 255;
    float sacc = 0.f;
#pragma unroll
    for (int w = 0; w < 8; ++w) sacc += pvp[w][oo][d];
    o0[oo][d] = sacc;
  }
  __syncthreads();

  // ---- phase 4: threads t<256 compute BOTH o's, one WfT column load ----
  if (t < DIM) {
    const int d = t;
    float f0 = 0.f, f1 = 0.f;
#pragma unroll 8
    for (int e4 = 0; e4 < 64; ++e4) {
      float oa[4], ob[4];
      f4arr(*(const float4*)&o0[0][e4 * 4], oa);
      f4arr(*(const float4*)&o0[1][e4 * 4], ob);
#pragma unroll
      for (int c = 0; c < 4; ++c) {
        float wv = WfT[(size_t)(e4 * 4 + c) * DIM + d];
        f0 = fmaf(oa[c], wv, f0);
        f1 = fmaf(ob[c], wv, f1);
      }
    }
    float bfv = bf[d];
    f0 += bfv; f1 += bfv;
    f0 = (f0 >= 0.f) ? f0 : NEG_SLOPE * f0;
    f1 = (f1 >= 0.f) ? f1 : NEG_SLOPE * f1;
    out[(size_t)(bo0 + 0) * DIM + d] = f0;
    out[(size_t)(bo0 + 1) * DIM + d] = f1;
  }
}

// ---------------------------------------------------------------------------
extern "C" void kernel_launch(void* const* d_in, const int* in_sizes, int n_in,
                              void* d_out, int out_size, void* d_ws, size_t ws_size,
                              hipStream_t stream) {
  const float* q    = (const float*)d_in[0];
  const float* k    = (const float*)d_in[1];
  const float* v    = (const float*)d_in[2];
  const int*   mask = (const int*)d_in[3];
  const float* W1   = (const float*)d_in[4];
  const float* b1   = (const float*)d_in[5];
  const float* W2   = (const float*)d_in[6];
  const float* b2   = (const float*)d_in[7];
  const float* Wf   = (const float*)d_in[8];
  const float* bf   = (const float*)d_in[9];

  float* out      = (float*)d_out;                    // (16,64,256)
  float* attn_out = out + (size_t)BATCH * NO * DIM;   // (16,64,512)

  float* Eq   = (float*)d_ws;                         // 1024 x 256
  float* Ek4  = Eq + (size_t)BATCH * NO * DIM;        // 16 x 64 x 512 x 4
  float* WfT  = Ek4 + (size_t)BATCH * DIM * NI;       // 256 x 256

  proj_kernel<<<592, 256, 0, stream>>>(q, k, W1, b1, Wf, mask, Eq, Ek4, WfT);
  attn_kernel<<<(BATCH * NO) / OT, 512, 0, stream>>>(Eq, Ek4, v, mask,
                                                     W2, b2, WfT, bf, out, attn_out);
}